// Round 8
// baseline (264.980 us; speedup 1.0000x reference)
//
#include <hip/hip_runtime.h>

// Problem constants (from reference)
#define NNODES 100000
#define NEDGES 3200000
#define DIM    128

typedef __bf16  bf16x8 __attribute__((ext_vector_type(8)));
typedef unsigned short u16;
typedef u16     u16x8  __attribute__((ext_vector_type(8)));
typedef float   f32x4  __attribute__((ext_vector_type(4)));
typedef unsigned int u32;
typedef u32     u32x4  __attribute__((ext_vector_type(4)));

__device__ __forceinline__ u16 f2bf(float f) {
    // round-to-nearest-even f32 -> bf16
    union { float f; unsigned int i; } c;
    c.f = f;
    unsigned int x = c.i;
    unsigned int rounding = 0x7fff + ((x >> 16) & 1);
    x += rounding;
    return (u16)(x >> 16);
}

__device__ __forceinline__ float asf(u32 u) {
    union { u32 i; float f; } c; c.i = u; return c.f;
}

__device__ __forceinline__ bf16x8 ldfrag_u16(const u16* p) {
    u16x8 u = *(const u16x8*)p;
    return __builtin_bit_cast(bf16x8, u);
}

// load 8 consecutive fp32, convert to bf16x8 fragment (RNE)
__device__ __forceinline__ bf16x8 ldfrag_f32(const float* p) {
    f32x4 a = *(const f32x4*)p;
    f32x4 b = *(const f32x4*)(p + 4);
    u16x8 u;
#pragma unroll
    for (int i = 0; i < 4; ++i) u[i] = f2bf(a[i]);
#pragma unroll
    for (int i = 0; i < 4; ++i) u[4 + i] = f2bf(b[i]);
    return __builtin_bit_cast(bf16x8, u);
}

// ---------------------------------------------------------------------------
// Kernel 1: CSR row_ptr from sorted edge_row via binary search.
__global__ void build_row_ptr(const int* __restrict__ edge_row,
                              int* __restrict__ row_ptr) {
    int n = blockIdx.x * blockDim.x + threadIdx.x;
    if (n > NNODES) return;
    int lo = 0, hi = NEDGES;
    while (lo < hi) {
        int mid = (lo + hi) >> 1;
        if (edge_row[mid] < n) lo = mid + 1; else hi = mid;
    }
    row_ptr[n] = lo;
}

// ---------------------------------------------------------------------------
// Kernel 2: Wt[n][k] = bf16(W[k][n])  (fp32 -> bf16 transpose, 128x128)
__global__ void prep_wt(const float* __restrict__ w, u16* __restrict__ wt) {
    int i = blockIdx.x * blockDim.x + threadIdx.x;
    if (i >= DIM * DIM) return;
    int k = i >> 7, n = i & 127;
    wt[n * DIM + k] = f2bf(w[k * DIM + n]);
}

// ---------------------------------------------------------------------------
// Kernel 3 (v3): y = bf16(x) @ bf16(W).  No block-wide staging, no barrier.
// Wave = 32 rows (two 16-row MFMA strips sharing each B-fragment).
// B-frags come straight from global wt (32KB, L2-resident broadcast).
// Epilogue: per-wave 4KB LDS bounce -> coalesced 1KB dwordx4 stores.
__global__ __launch_bounds__(256) void gemm_xw(const float* __restrict__ x,
                                               const u16* __restrict__ wt,
                                               u16* __restrict__ y) {
    __shared__ u16 ybounce[4][16 * DIM];      // 4 waves x 4KB

    int tid  = threadIdx.x;
    int wave = __builtin_amdgcn_readfirstlane(tid >> 6);
    int lane = tid & 63;
    int quad = lane >> 4, l16 = lane & 15;
    int mBase = (blockIdx.x * 4 + wave) * 32;
    if (mBase >= NNODES) return;          // no barriers anywhere: safe

    const float* xrow0 = x + (size_t)(mBase + l16) * DIM + quad * 8;
    const float* xrow1 = xrow0 + 16 * DIM;

    f32x4 acc0[8], acc1[8];
#pragma unroll
    for (int nt = 0; nt < 8; ++nt) {
        acc0[nt] = (f32x4){0.f, 0.f, 0.f, 0.f};
        acc1[nt] = (f32x4){0.f, 0.f, 0.f, 0.f};
    }

#pragma unroll
    for (int kb = 0; kb < 4; ++kb) {
        bf16x8 a0 = ldfrag_f32(xrow0 + kb * 32);
        bf16x8 a1 = ldfrag_f32(xrow1 + kb * 32);
#pragma unroll
        for (int nt = 0; nt < 8; ++nt) {
            bf16x8 b = ldfrag_u16(wt + (nt * 16 + l16) * DIM + kb * 32 + quad * 8);
            acc0[nt] = __builtin_amdgcn_mfma_f32_16x16x32_bf16(a0, b, acc0[nt], 0, 0, 0);
            acc1[nt] = __builtin_amdgcn_mfma_f32_16x16x32_bf16(a1, b, acc1[nt], 0, 0, 0);
        }
    }

    // two strips sequentially through the per-wave bounce tile
    u16* yb = ybounce[wave];
#pragma unroll
    for (int strip = 0; strip < 2; ++strip) {
        f32x4* acc = strip == 0 ? acc0 : acc1;
        int rBase = mBase + strip * 16;
#pragma unroll
        for (int nt = 0; nt < 8; ++nt) {
            int col = nt * 16 + l16;
#pragma unroll
            for (int r = 0; r < 4; ++r)
                yb[(quad * 4 + r) * DIM + col] = f2bf(acc[nt][r]);
        }
        // in-wave LDS dependency only; compiler inserts lgkmcnt waits
#pragma unroll
        for (int j = 0; j < 4; ++j) {
            int lr = j * 4 + quad;            // 0..15
            u16x8 t = *(const u16x8*)(yb + lr * DIM + l16 * 8);
            *(u16x8*)(y + (size_t)(rBase + lr) * DIM + l16 * 8) = t;
        }
    }
}

// ---------------------------------------------------------------------------
// Kernel 4: out[n][:] = bias + sum_{e in row n} val[e] * y[col[e]][:]
// One wave per row (wave-uniform row -> scalar metadata loads).
// QUAD-EDGE GATHER: one global_load_dwordx4 fetches 16B chunks of FOUR
// different y-rows (lane l: edge grp=l>>4, chunk sub=l&15) = 1KB/instruction.
// __shfl_xor(16|32) tree merges the 4 groups at the end.
__global__ __launch_bounds__(256) void spmm(const int* __restrict__ row_ptr,
                                            const int* __restrict__ ecol,
                                            const float* __restrict__ eval,
                                            const u16* __restrict__ y,
                                            const float* __restrict__ bias,
                                            float* __restrict__ out) {
    int lane = threadIdx.x & 63;
    int row  = __builtin_amdgcn_readfirstlane(blockIdx.x * 4 + (threadIdx.x >> 6));
    if (row >= NNODES) return;

    int lo = row_ptr[row];
    int hi = row_ptr[row + 1];

    int grp = lane >> 4;   // which edge of the quad this lane serves
    int sub = lane & 15;   // which 16B chunk of the 256B y-row

    float acc[8];
#pragma unroll
    for (int j = 0; j < 8; ++j) acc[j] = 0.f;

    const u16* ychunk = y + sub * 8;

    int e = lo;
    // main loop: 16 edges per iteration, 4 gather insts of 1KB each
    for (; e + 16 <= hi; e += 16) {
#pragma unroll
        for (int b = 0; b < 4; ++b) {
            int e0 = e + b * 4;
            int   c0 = ecol[e0], c1 = ecol[e0 + 1], c2 = ecol[e0 + 2], c3 = ecol[e0 + 3];
            float v0 = eval[e0], v1 = eval[e0 + 1], v2 = eval[e0 + 2], v3 = eval[e0 + 3];
            int   c = grp < 2 ? (grp == 0 ? c0 : c1) : (grp == 2 ? c2 : c3);
            float v = grp < 2 ? (grp == 0 ? v0 : v1) : (grp == 2 ? v2 : v3);
            u32x4 q = *(const u32x4*)(ychunk + (size_t)c * DIM);
#pragma unroll
            for (int j = 0; j < 4; ++j) {
                acc[2 * j]     += v * asf(q[j] << 16);
                acc[2 * j + 1] += v * asf(q[j] & 0xffff0000u);
            }
        }
    }
    // tail: up to 4 edges per pass, padded with v=0 on the repeated index
    for (; e < hi; e += 4) {
        int rem = hi - e;   // >= 1, uniform
        int i1 = rem > 1 ? e + 1 : e, i2 = rem > 2 ? e + 2 : e, i3 = rem > 3 ? e + 3 : e;
        int   c0 = ecol[e],  c1 = ecol[i1], c2 = ecol[i2], c3 = ecol[i3];
        float v0 = eval[e];
        float v1 = rem > 1 ? eval[i1] : 0.f;
        float v2 = rem > 2 ? eval[i2] : 0.f;
        float v3 = rem > 3 ? eval[i3] : 0.f;
        int   c = grp < 2 ? (grp == 0 ? c0 : c1) : (grp == 2 ? c2 : c3);
        float v = grp < 2 ? (grp == 0 ? v0 : v1) : (grp == 2 ? v2 : v3);
        u32x4 q = *(const u32x4*)(ychunk + (size_t)c * DIM);
#pragma unroll
        for (int j = 0; j < 4; ++j) {
            acc[2 * j]     += v * asf(q[j] << 16);
            acc[2 * j + 1] += v * asf(q[j] & 0xffff0000u);
        }
    }

    // merge the 4 lane-groups (same sub, grp 0..3)
#pragma unroll
    for (int j = 0; j < 8; ++j) {
        acc[j] += __shfl_xor(acc[j], 16);
        acc[j] += __shfl_xor(acc[j], 32);
    }

    if (grp == 0) {
        float* orow = out + (size_t)row * DIM + sub * 8;
        f32x4 o0, o1;
#pragma unroll
        for (int j = 0; j < 4; ++j) {
            o0[j] = acc[j]     + bias[sub * 8 + j];
            o1[j] = acc[4 + j] + bias[sub * 8 + 4 + j];
        }
        __builtin_nontemporal_store(o0, (f32x4*)orow);
        __builtin_nontemporal_store(o1, (f32x4*)(orow + 4));
    }
}

// ---------------------------------------------------------------------------
extern "C" void kernel_launch(void* const* d_in, const int* in_sizes, int n_in,
                              void* d_out, int out_size, void* d_ws, size_t ws_size,
                              hipStream_t stream) {
    const float* x        = (const float*)d_in[0];  // [NNODES, DIM] fp32
    const int*   edge_row = (const int*)d_in[1];    // [NEDGES] int32 (sorted)
    const int*   edge_col = (const int*)d_in[2];    // [NEDGES] int32
    const float* edge_val = (const float*)d_in[3];  // [NEDGES] fp32
    const float* weight   = (const float*)d_in[4];  // [DIM, DIM] fp32
    const float* bias     = (const float*)d_in[5];  // [DIM] fp32
    float* out = (float*)d_out;                     // [NNODES, DIM] fp32

    char* ws = (char*)d_ws;
    // layout: y bf16 [NNODES*DIM] | row_ptr int[NNODES+1] | Wt bf16 [DIM*DIM]
    u16* y       = (u16*)ws;                               // 25,600,000 B
    int* row_ptr = (int*)(ws + (size_t)NNODES * DIM * 2);  // 400,004 B
    u16* wt      = (u16*)(ws + 26000128);                  // 32,768 B (16B aligned)

    prep_wt<<<(DIM * DIM + 255) / 256, 256, 0, stream>>>(weight, wt);
    build_row_ptr<<<(NNODES + 1 + 255) / 256, 256, 0, stream>>>(edge_row, row_ptr);

    // y = x @ W : wave = 32 rows, block = 128 rows -> 782 blocks
    gemm_xw<<<(NNODES + 127) / 128, 256, 0, stream>>>(x, wt, y);

    // out = A @ y + bias : one wave per row, 4 waves/block -> 25000 blocks
    spmm<<<NNODES / 4, 256, 0, stream>>>(row_ptr, edge_col, edge_val, y, bias, out);
}